// Round 1
// 410.165 us; speedup vs baseline: 1.0213x; 1.0213x over previous
//
#include <hip/hip_runtime.h>
#include <hip/hip_bf16.h>

// Problem constants
#define NA 8192      // oscillators in bank a (mask rows)
#define NB 8192      // oscillators in bank b (mask cols = GEMM K)
#define NBATCH 64
#define NC 128       // GEMM N: interleaved [cos_b, sin_b] cols, c=2b (cos), 2b+1 (sin)
#define BM 128       // output rows per block
#define WM 32        // output rows per wave (2 A-fragments of 16)
#define SPLITK 8
#define KCHUNK (NB / SPLITK)     // 1024
#define NBLK (SPLITK * NA / BM)  // 512 gemm blocks

// workspace layout
#define XT_BYTES (NC * NB * 2)            // 2 MiB bf16 XtF (fragment-ordered)
#define CTR_OFF  XT_BYTES                 // count (int)
#define PBLK_OFF (CTR_OFF + 512)          // 128 x NBLK f32 partials, TRANSPOSED (256 KiB)

typedef __bf16 bf16x8 __attribute__((ext_vector_type(8)));
typedef float  f32x4  __attribute__((ext_vector_type(4)));
typedef int    ivec4  __attribute__((ext_vector_type(4)));
typedef unsigned short u16x8 __attribute__((ext_vector_type(8)));

// ---------------- prep: phases_b -> XtF in MFMA B-fragment order --------------
// Element (k, c) stored at ((kstep*8 + t)*64 + quad*16 + m)*8 + e
//   kstep=k>>5, quad=(k>>3)&3, e=k&7, t=c>>4, m=c&15  (natural k order)
// Each thread owns 8 consecutive k's of one batch -> two 16-B stores (was 2-B
// scalar stores). Also zeroes the popcount accumulator (stream-ordered vs gemm).
__global__ __launch_bounds__(256) void prep_b_kernel(
    const float* __restrict__ pb, __hip_bfloat16* __restrict__ Xtf,
    int* __restrict__ count)
{
    int tid = blockIdx.x * 256 + threadIdx.x;   // 0 .. NBATCH*NB/8-1 = 65535
    if (tid == 0) *count = 0;

    int b  = tid >> 10;          // batch 0..63
    int kg = tid & 1023;         // k-group (8 k's) 0..1023
    int k  = kg << 3;

    const float4* pp = reinterpret_cast<const float4*>(pb + ((size_t)b << 13) + k);
    float4 v0 = pp[0], v1 = pp[1];
    float ph[8] = {v0.x, v0.y, v0.z, v0.w, v1.x, v1.y, v1.z, v1.w};

    u16x8 cv, sv;
#pragma unroll
    for (int e = 0; e < 8; ++e) {
        float s, c;
        __sincosf(ph[e], &s, &c);
        cv[e] = __builtin_bit_cast(unsigned short, __float2bfloat16(c));
        sv[e] = __builtin_bit_cast(unsigned short, __float2bfloat16(s));
    }

    int kstep = kg >> 2;         // k>>5
    int quad  = kg & 3;          // (k>>3)&3
    int t     = b >> 3;          // (2b)>>4 == (2b+1)>>4
    int m0    = (2 * b) & 15;
    size_t base = (((size_t)(kstep * 8 + t) * 64) + quad * 16 + m0) * 8;  // elements
    *reinterpret_cast<u16x8*>(&Xtf[base])     = cv;   // cos column (c = 2b)
    *reinterpret_cast<u16x8*>(&Xtf[base + 8]) = sv;   // sin column (c = 2b+1)
}

// ---------------- fused GEMM + batch-reduce epilogue --------------------------
// P[i][c] = sum_k mask[i][k] * X[k][c]  (never materialized)
// C/D: col=lane&15, row=quad*4+reg (measured m89/m91)
//
// v1 changes:
//  * explicit 2-stage SW pipeline: mask regs AND B-frags for kstep s+1 are
//    issued before the MFMAs of kstep s, so the compiler emits a counted
//    s_waitcnt vmcnt(12) (next step's 12 loads stay in flight) instead of a
//    full per-iteration drain. Load order matters: next-A and next-B issue
//    together BEFORE consuming the current regs (in-order vmcnt).
//  * mask in {0,1} (problem spec): bf16 convert via (x|y<<16)*0x3F80 (2 VALU
//    per packed pair vs cmp+cndmask+or), popcount via __popc(pair).
//  * Pblk written transposed [idx][blk] so final_kernel reads coalesced.
// NOTE: __launch_bounds__(256,2) is the measured optimum from the prior
// session — (256,3) forces spills whose scratch traffic adds to the HBM mask
// stream. Do not re-raise.
struct Bfrags { bf16x8 v[8]; };

__device__ __forceinline__ Bfrags load_b(const bf16x8* __restrict__ fx) {
    Bfrags b;
#pragma unroll
    for (int t = 0; t < 8; ++t) b.v[t] = fx[t * 64];
    return b;
}

__device__ __forceinline__ bf16x8 conv_a(ivec4 r0, ivec4 r1, int& cnt) {
    // mask values are exactly {0,1}: pair has single bits at 0 and 16;
    // *0x3F80 turns each into bf16 1.0 in the right half (no carry: 0x3F80<2^16)
    unsigned p0 = (unsigned)r0.x | ((unsigned)r0.y << 16);
    unsigned p1 = (unsigned)r0.z | ((unsigned)r0.w << 16);
    unsigned p2 = (unsigned)r1.x | ((unsigned)r1.y << 16);
    unsigned p3 = (unsigned)r1.z | ((unsigned)r1.w << 16);
    cnt += __popc(p0) + __popc(p1) + __popc(p2) + __popc(p3);
    uint4 u;
    u.x = p0 * 0x3F80u;
    u.y = p1 * 0x3F80u;
    u.z = p2 * 0x3F80u;
    u.w = p3 * 0x3F80u;
    return __builtin_bit_cast(bf16x8, u);
}

__global__ __launch_bounds__(256, 2) void gemm_kernel(
    const int* __restrict__ mask, const __hip_bfloat16* __restrict__ Xtfg,
    const float* __restrict__ pa,
    float* __restrict__ Pblk, int* __restrict__ count)
{
    const int tid  = threadIdx.x;
    const int wave = tid >> 6;
    const int lane = tid & 63;
    const int quad = lane >> 4;
    const int m    = lane & 15;
    const int itile = blockIdx.x;       // 0..63
    const int kc    = blockIdx.y;       // 0..SPLITK-1
    const int k0    = kc * KCHUNK;

    const int rowbase = itile * BM + wave * WM;
    const bf16x8* __restrict__ xf = reinterpret_cast<const bf16x8*>(Xtfg);

    f32x4 acc[2][8];
#pragma unroll
    for (int f = 0; f < 2; ++f)
#pragma unroll
        for (int t = 0; t < 8; ++t)
            acc[f][t] = (f32x4){0.f, 0.f, 0.f, 0.f};

    int cnt = 0;

    const int* mrow0 = mask + (size_t)(rowbase + m) * NB + quad * 8;
    const int* mrow1 = mrow0 + (size_t)16 * NB;

    auto load_a = [&](int kkk, ivec4& a00, ivec4& a01, ivec4& a10, ivec4& a11) {
        const ivec4* p0 = reinterpret_cast<const ivec4*>(mrow0 + kkk);
        a00 = __builtin_nontemporal_load(p0);
        a01 = __builtin_nontemporal_load(p0 + 1);
        const ivec4* p1 = reinterpret_cast<const ivec4*>(mrow1 + kkk);
        a10 = __builtin_nontemporal_load(p1);
        a11 = __builtin_nontemporal_load(p1 + 1);
    };

    ivec4 x00, x01, x10, x11;  Bfrags bx;
    ivec4 y00, y01, y10, y11;  Bfrags by;

    // prologue: stage kstep k0
    load_a(k0, x00, x01, x10, x11);
    bx = load_b(xf + (size_t)(k0 >> 5) * 512 + lane);

    for (int kk = k0; kk < k0 + KCHUNK; kk += 64) {   // 2 ksteps / iter, 16 iters
        // issue kstep kk+32 (A then B) BEFORE consuming kstep kk
        load_a(kk + 32, y00, y01, y10, y11);
        by = load_b(xf + (size_t)((kk + 32) >> 5) * 512 + lane);
        {
            bf16x8 a0 = conv_a(x00, x01, cnt);
            bf16x8 a1 = conv_a(x10, x11, cnt);
#pragma unroll
            for (int t = 0; t < 8; ++t) {
                acc[0][t] = __builtin_amdgcn_mfma_f32_16x16x32_bf16(a0, bx.v[t], acc[0][t], 0, 0, 0);
                acc[1][t] = __builtin_amdgcn_mfma_f32_16x16x32_bf16(a1, bx.v[t], acc[1][t], 0, 0, 0);
            }
        }
        // issue kstep kk+64 (wrap to k0 on the last iter: cheap, in-bounds)
        const int kn = (kk + 64 < k0 + KCHUNK) ? (kk + 64) : k0;
        load_a(kn, x00, x01, x10, x11);
        bx = load_b(xf + (size_t)(kn >> 5) * 512 + lane);
        {
            bf16x8 a0 = conv_a(y00, y01, cnt);
            bf16x8 a1 = conv_a(y10, y11, cnt);
#pragma unroll
            for (int t = 0; t < 8; ++t) {
                acc[0][t] = __builtin_amdgcn_mfma_f32_16x16x32_bf16(a0, by.v[t], acc[0][t], 0, 0, 0);
                acc[1][t] = __builtin_amdgcn_mfma_f32_16x16x32_bf16(a1, by.v[t], acc[1][t], 0, 0, 0);
            }
        }
    }

    // ---- fused epilogue: project partial P onto (ca,sa) and reduce ----
    __shared__ float lred[4][64][2];
    const int odd = m & 1;

#pragma unroll
    for (int t = 0; t < 8; ++t) {
        const int b = t * 8 + (m >> 1);           // batch index for this column
        float rc = 0.f, ic = 0.f;
#pragma unroll
        for (int f = 0; f < 2; ++f)
#pragma unroll
            for (int r = 0; r < 4; ++r) {
                int row = rowbase + f * 16 + quad * 4 + r;
                float ph = pa[(size_t)b * NA + row];
                float sn, cs;
                __sincosf(ph, &sn, &cs);
                float Ax = odd ? sn : cs;          // real-part weight
                float Bx = odd ? -cs : sn;         // imag-part weight
                rc = fmaf(Ax, acc[f][t][r], rc);
                ic = fmaf(Bx, acc[f][t][r], ic);
            }
        // combine col pair (even+odd), then the 4 quads
        rc += __shfl_xor(rc, 1);  ic += __shfl_xor(ic, 1);
        rc += __shfl_xor(rc, 16); ic += __shfl_xor(ic, 16);
        rc += __shfl_xor(rc, 32); ic += __shfl_xor(ic, 32);
        if (quad == 0 && !odd) {
            lred[wave][b][0] = rc;
            lred[wave][b][1] = ic;
        }
    }
    __syncthreads();

    if (tid < 128) {
        float s = lred[0][tid >> 1][tid & 1] + lred[1][tid >> 1][tid & 1]
                + lred[2][tid >> 1][tid & 1] + lred[3][tid >> 1][tid & 1];
        int bid = blockIdx.y * 64 + blockIdx.x;
        Pblk[(size_t)tid * NBLK + bid] = s;       // transposed: coalesced final read
    }

    // mask popcount: wave reduce then one atomic per wave
#pragma unroll
    for (int off = 32; off > 0; off >>= 1) cnt += __shfl_down(cnt, off);
    if (lane == 0) atomicAdd(count, cnt);
}

// ---------------- final: sum block partials, magnitude, normalize -------------
// 64 blocks (one per batch), coalesced reads of the transposed Pblk.
__global__ __launch_bounds__(256) void final_kernel(
    const float* __restrict__ Pblk, const int* __restrict__ count,
    float* __restrict__ out)
{
    const int b = blockIdx.x;           // 0..63
    const int t = threadIdx.x;          // 0..255

    float r = 0.f, im = 0.f;
#pragma unroll
    for (int blk = t; blk < NBLK; blk += 256) {
        r  += Pblk[(size_t)(2 * b)     * NBLK + blk];
        im += Pblk[(size_t)(2 * b + 1) * NBLK + blk];
    }
#pragma unroll
    for (int off = 32; off > 0; off >>= 1) {
        r  += __shfl_down(r, off);
        im += __shfl_down(im, off);
    }

    __shared__ float red[8];
    if ((t & 63) == 0) { red[(t >> 6) * 2] = r; red[(t >> 6) * 2 + 1] = im; }
    __syncthreads();

    if (t == 0) {
        float R = red[0] + red[2] + red[4] + red[6];
        float I = red[1] + red[3] + red[5] + red[7];
        float n = fmaxf((float)(*count), 1.0f);
        out[b] = sqrtf(R * R + I * I) / n;
    }
}

extern "C" void kernel_launch(void* const* d_in, const int* in_sizes, int n_in,
                              void* d_out, int out_size, void* d_ws, size_t ws_size,
                              hipStream_t stream) {
    const float* pa   = (const float*)d_in[0];   // phases_a (64, 8192) f32
    const float* pb   = (const float*)d_in[1];   // phases_b (64, 8192) f32
    const int*   mask = (const int*)d_in[2];     // coupling_mask (8192, 8192) i32
    float* out = (float*)d_out;                  // (64,) f32

    char* ws = (char*)d_ws;
    __hip_bfloat16* Xtf = (__hip_bfloat16*)ws;
    int*   count = (int*)(ws + CTR_OFF);
    float* Pblk  = (float*)(ws + PBLK_OFF);

    prep_b_kernel<<<(NBATCH * NB / 8) / 256, 256, 0, stream>>>(pb, Xtf, count);

    dim3 g(NA / BM, SPLITK);
    gemm_kernel<<<g, 256, 0, stream>>>(mask, Xtf, pa, Pblk, count);

    final_kernel<<<NBATCH, 256, 0, stream>>>(Pblk, count, out);
}